// Round 1
// baseline (319.281 us; speedup 1.0000x reference)
//
#include <hip/hip_runtime.h>
#include <math.h>

#define Bsz  2
#define Ntok 256
#define Ddim 512
#define Hdim 2048
#define Mrows (Bsz * Ntok)   // 512

// ---------------------------------------------------------------------------
// Distance kernel.
// role 0 (blocks 0..127):   dv[b,i] = (1/N) * sum_j sum_d |xv[b,i,d]-xa[b,j,d]|
// role 1 (blocks 128..255): da[b,j] = (1/N) * sum_i sum_d |xa[b,j,d]-xv[b,i,d]|
// Each block handles 4 query rows; query values live in registers because a
// thread only ever touches d in {tid, tid+256}.
// ---------------------------------------------------------------------------
__global__ __launch_bounds__(256) void dist_kernel(const float* __restrict__ xv,
                                                   const float* __restrict__ xa,
                                                   float* __restrict__ dv,
                                                   float* __restrict__ da) {
    __shared__ float red[4][4];   // [wave][row]
    int bx   = blockIdx.x;
    int role = bx >> 7;           // 0: dv, 1: da
    int g    = bx & 127;
    int b    = g >> 6;            // batch
    int i0   = (g & 63) << 2;     // first of 4 query rows
    const float* Q    = role ? xa : xv;
    const float* S    = role ? xv : xa;
    float*       outp = role ? da : dv;

    int tid = threadIdx.x;
    int t0 = tid, t1 = tid + 256;
    const float* Qb = Q + ((size_t)b * Ntok + i0) * Ddim;
    const float* Sb = S + (size_t)b * Ntok * Ddim;

    float q0[4], q1[4];
#pragma unroll
    for (int r = 0; r < 4; ++r) {
        q0[r] = Qb[r * Ddim + t0];
        q1[r] = Qb[r * Ddim + t1];
    }
    float acc[4] = {0.f, 0.f, 0.f, 0.f};
    for (int j = 0; j < Ntok; ++j) {
        float s0 = Sb[j * Ddim + t0];
        float s1 = Sb[j * Ddim + t1];
#pragma unroll
        for (int r = 0; r < 4; ++r)
            acc[r] += fabsf(q0[r] - s0) + fabsf(q1[r] - s1);
    }
    int lane = tid & 63, wv = tid >> 6;
#pragma unroll
    for (int r = 0; r < 4; ++r) {
        float v = acc[r];
#pragma unroll
        for (int off = 32; off; off >>= 1) v += __shfl_down(v, off);
        if (lane == 0) red[wv][r] = v;
    }
    __syncthreads();
    if (tid < 4) {
        float v = red[0][tid] + red[1][tid] + red[2][tid] + red[3][tid];
        outp[b * Ntok + i0 + tid] = v * (1.0f / 256.0f);
    }
}

// ---------------------------------------------------------------------------
// fp32 tiled GEMM: C[z] = act( diag(scale[z]) * A[z] @ Bw[z] + bias[z] )
// 64x64 tile, BK=16, 256 threads, 4x4 microtile. z fuses the v/a streams.
// M is fixed at Mrows=512 via grid.y; N via grid.x.
// ---------------------------------------------------------------------------
struct GemmPtrs {
    const float* A[2];
    const float* Bw[2];
    const float* bias[2];
    const float* scale[2];   // nullptr -> no row scaling
    float*       C[2];
};

template <int GELU>
__global__ __launch_bounds__(256) void gemm_kernel(GemmPtrs p, int Kdim,
                                                   int lda, int ldb, int ldc) {
    __shared__ float As[16][68];   // [k][m], +4 pad keeps rows 16B-aligned, breaks conflicts
    __shared__ float Bs[16][64];   // [k][n]

    int zi = blockIdx.z;
    const float* A     = p.A[zi];
    const float* Bw    = p.Bw[zi];
    const float* bias  = p.bias[zi];
    const float* scale = p.scale[zi];
    float*       C     = p.C[zi];

    int tid = threadIdx.x;
    int tx = tid & 15, ty = tid >> 4;
    int m0 = blockIdx.y << 6, n0 = blockIdx.x << 6;

    // A-tile load map: 4 threads per row, each loads float4 of k
    int am = tid >> 2;            // 0..63
    int ak = (tid & 3) << 2;      // 0,4,8,12
    // B-tile load map: 16 threads per k-row, each loads float4 of n
    int bk = tid >> 4;            // 0..15
    int bn = (tid & 15) << 2;     // 0..60

    float s = scale ? scale[m0 + am] : 1.0f;

    float c[4][4];
#pragma unroll
    for (int i = 0; i < 4; ++i)
#pragma unroll
        for (int j = 0; j < 4; ++j) c[i][j] = 0.0f;

    const float* Aptr = A + (size_t)(m0 + am) * lda + ak;
    const float* Bptr = Bw + (size_t)bk * ldb + n0 + bn;

    for (int kt = 0; kt < Kdim; kt += 16) {
        float4 av = *(const float4*)(Aptr + kt);
        av.x *= s; av.y *= s; av.z *= s; av.w *= s;
        As[ak + 0][am] = av.x;
        As[ak + 1][am] = av.y;
        As[ak + 2][am] = av.z;
        As[ak + 3][am] = av.w;
        *(float4*)&Bs[bk][bn] = *(const float4*)(Bptr + (size_t)kt * ldb);
        __syncthreads();
#pragma unroll
        for (int kk = 0; kk < 16; ++kk) {
            float4 a4 = *(const float4*)&As[kk][ty << 2];
            float4 b4 = *(const float4*)&Bs[kk][tx << 2];
            float ar[4] = {a4.x, a4.y, a4.z, a4.w};
            float br[4] = {b4.x, b4.y, b4.z, b4.w};
#pragma unroll
            for (int i = 0; i < 4; ++i)
#pragma unroll
                for (int j = 0; j < 4; ++j)
                    c[i][j] = fmaf(ar[i], br[j], c[i][j]);
        }
        __syncthreads();
    }

#pragma unroll
    for (int i = 0; i < 4; ++i) {
        int m = m0 + (ty << 2) + i;
#pragma unroll
        for (int j = 0; j < 4; ++j) {
            int n = n0 + (tx << 2) + j;
            float v = c[i][j] + bias[n];
            if (GELU) v = 0.5f * v * (1.0f + erff(v * 0.70710678118654752f));
            C[(size_t)m * ldc + n] = v;
        }
    }
}

extern "C" void kernel_launch(void* const* d_in, const int* in_sizes, int n_in,
                              void* d_out, int out_size, void* d_ws, size_t ws_size,
                              hipStream_t stream) {
    const float* x_v  = (const float*)d_in[0];
    const float* x_a  = (const float*)d_in[1];
    const float* W1v  = (const float*)d_in[2];
    const float* b1v  = (const float*)d_in[3];
    const float* W1a  = (const float*)d_in[4];
    const float* b1a  = (const float*)d_in[5];
    const float* Wmv  = (const float*)d_in[6];
    const float* bmv  = (const float*)d_in[7];
    const float* Wma  = (const float*)d_in[8];
    const float* bma  = (const float*)d_in[9];
    const float* Wout = (const float*)d_in[10];
    const float* bout = (const float*)d_in[11];
    float* out = (float*)d_out;

    float* ws   = (float*)d_ws;
    float* dv   = ws;                              // 512
    float* da   = ws + 512;                        // 512
    float* g1v  = ws + 1024;                       // M*H = 1M floats
    float* g1a  = g1v + (size_t)Mrows * Hdim;      // 1M floats
    float* comb = g1a + (size_t)Mrows * Hdim;      // M*2D = 512K floats

    // 1) pairwise Manhattan distance row/col means
    dist_kernel<<<dim3(256), dim3(256), 0, stream>>>(x_v, x_a, dv, da);

    // 2) g1 = gelu(diag(d)*x @ W1 + b1)   [M,H], fused over v/a via grid.z
    GemmPtrs g1;
    g1.A[0] = x_v; g1.A[1] = x_a;
    g1.Bw[0] = W1v; g1.Bw[1] = W1a;
    g1.bias[0] = b1v; g1.bias[1] = b1a;
    g1.scale[0] = dv; g1.scale[1] = da;
    g1.C[0] = g1v; g1.C[1] = g1a;
    gemm_kernel<1><<<dim3(Hdim / 64, Mrows / 64, 2), dim3(256), 0, stream>>>(
        g1, Ddim, Ddim, Hdim, Hdim);

    // 3) comb[:, 0:512] = g1v @ Wmv + bmv ; comb[:, 512:1024] = g1a @ Wma + bma
    GemmPtrs g2;
    g2.A[0] = g1v; g2.A[1] = g1a;
    g2.Bw[0] = Wmv; g2.Bw[1] = Wma;
    g2.bias[0] = bmv; g2.bias[1] = bma;
    g2.scale[0] = nullptr; g2.scale[1] = nullptr;
    g2.C[0] = comb; g2.C[1] = comb + Ddim;
    gemm_kernel<0><<<dim3(Ddim / 64, Mrows / 64, 2), dim3(256), 0, stream>>>(
        g2, Hdim, Hdim, Ddim, 2 * Ddim);

    // 4) out = comb @ Wout + bout   [M, D]
    GemmPtrs g3;
    g3.A[0] = comb; g3.A[1] = comb;
    g3.Bw[0] = Wout; g3.Bw[1] = Wout;
    g3.bias[0] = bout; g3.bias[1] = bout;
    g3.scale[0] = nullptr; g3.scale[1] = nullptr;
    g3.C[0] = out; g3.C[1] = out;
    gemm_kernel<0><<<dim3(Ddim / 64, Mrows / 64, 1), dim3(256), 0, stream>>>(
        g3, 2 * Ddim, 2 * Ddim, Ddim, Ddim);
}

// Round 2
// 165.016 us; speedup vs baseline: 1.9349x; 1.9349x over previous
//
#include <hip/hip_runtime.h>
#include <math.h>

#define Bsz  2
#define Ntok 256
#define Ddim 512
#define Hdim 2048
#define Mrows (Bsz * Ntok)   // 512

typedef __bf16 bf16_8 __attribute__((ext_vector_type(8)));
typedef __bf16 bf16_4 __attribute__((ext_vector_type(4)));
typedef float  f32x4_t __attribute__((ext_vector_type(4)));

// ---------------------------------------------------------------------------
// Distance kernel (unchanged from R1 — verified correct).
// role 0 (blocks 0..127):   dv[b,i] = (1/N) * sum_j sum_d |xv[b,i,d]-xa[b,j,d]|
// role 1 (blocks 128..255): da[b,j]
// ---------------------------------------------------------------------------
__global__ __launch_bounds__(256) void dist_kernel(const float* __restrict__ xv,
                                                   const float* __restrict__ xa,
                                                   float* __restrict__ dv,
                                                   float* __restrict__ da) {
    __shared__ float red[4][4];
    int bx   = blockIdx.x;
    int role = bx >> 7;
    int g    = bx & 127;
    int b    = g >> 6;
    int i0   = (g & 63) << 2;
    const float* Q    = role ? xa : xv;
    const float* S    = role ? xv : xa;
    float*       outp = role ? da : dv;

    int tid = threadIdx.x;
    int t0 = tid, t1 = tid + 256;
    const float* Qb = Q + ((size_t)b * Ntok + i0) * Ddim;
    const float* Sb = S + (size_t)b * Ntok * Ddim;

    float q0[4], q1[4];
#pragma unroll
    for (int r = 0; r < 4; ++r) {
        q0[r] = Qb[r * Ddim + t0];
        q1[r] = Qb[r * Ddim + t1];
    }
    float acc[4] = {0.f, 0.f, 0.f, 0.f};
    for (int j = 0; j < Ntok; ++j) {
        float s0 = Sb[j * Ddim + t0];
        float s1 = Sb[j * Ddim + t1];
#pragma unroll
        for (int r = 0; r < 4; ++r)
            acc[r] += fabsf(q0[r] - s0) + fabsf(q1[r] - s1);
    }
    int lane = tid & 63, wv = tid >> 6;
#pragma unroll
    for (int r = 0; r < 4; ++r) {
        float v = acc[r];
#pragma unroll
        for (int off = 32; off; off >>= 1) v += __shfl_down(v, off);
        if (lane == 0) red[wv][r] = v;
    }
    __syncthreads();
    if (tid < 4) {
        float v = red[0][tid] + red[1][tid] + red[2][tid] + red[3][tid];
        outp[b * Ntok + i0 + tid] = v * (1.0f / 256.0f);
    }
}

// ---------------------------------------------------------------------------
// Fused transpose+cast for all 5 weight matrices: src fp32 [K][N] row-major
// -> dst bf16 [N][K] row-major, so GEMM B-frags are contiguous-k b128 reads.
// One launch; linear block id mapped to (matrix, tile) via a prefix table.
// ---------------------------------------------------------------------------
struct TPtrs {
    const float* src[5];
    __bf16*      dst[5];
};

__global__ __launch_bounds__(256) void transpose_all(TPtrs p) {
    // matrices: W1v[512][2048], W1a[512][2048], Wmv[2048][512], Wma[2048][512], Wout[1024][512]
    const int Ks[5]  = {512, 512, 2048, 2048, 1024};
    const int Ns[5]  = {2048, 2048, 512, 512, 512};
    const int off[6] = {0, 1024, 2048, 3072, 4096, 4608};  // (N/32)*(K/32) prefix

    int b = blockIdx.x;
    int mi = 0;
    while (b >= off[mi + 1]) ++mi;
    int local = b - off[mi];
    int shift = (mi < 2) ? 6 : 4;         // N/32 = 64 for W1*, else 16
    int bx = local & ((1 << shift) - 1);  // n-tile
    int by = local >> shift;              // k-tile
    const float* src = p.src[mi];
    __bf16*      dst = p.dst[mi];
    int K = Ks[mi], N = Ns[mi];
    int n0 = bx << 5, k0 = by << 5;

    __shared__ float tile[32][33];
    int t = threadIdx.x;
    int kl = t >> 3, nl = (t & 7) << 2;
    float4 v = *(const float4*)&src[(size_t)(k0 + kl) * N + n0 + nl];
    tile[kl][nl + 0] = v.x;
    tile[kl][nl + 1] = v.y;
    tile[kl][nl + 2] = v.z;
    tile[kl][nl + 3] = v.w;
    __syncthreads();
    int nl2 = t >> 3, kl2 = (t & 7) << 2;
    bf16_4 o;
#pragma unroll
    for (int i = 0; i < 4; ++i) o[i] = (__bf16)tile[kl2 + i][nl2];
    *(bf16_4*)&dst[(size_t)(n0 + nl2) * K + k0 + kl2] = o;
}

// ---------------------------------------------------------------------------
// bf16 MFMA GEMM: C[z] = act( (diag(scale[z]) * A[z]) @ B[z] + bias[z] )
// A: [M][K] (fp32 if AFP32 — scaled+cast during staging — else bf16)
// BT: bf16 [N][K] (pre-transposed weights)
// 64x64 tile, BK=32, 256 threads = 4 waves, each wave a 32x32 quadrant
// via 2x2 of v_mfma_f32_16x16x32_bf16. fp32 accumulate.
// ---------------------------------------------------------------------------
struct GPtrs {
    const void*   A[2];
    const __bf16* BT[2];
    const float*  bias[2];
    const float*  scale[2];
    void*         C[2];
};

template <int GELU, int AFP32, int OUTBF16>
__global__ __launch_bounds__(256) void mfma_gemm(GPtrs p, int Kdim, int ldc) {
    __shared__ __align__(16) __bf16 As[64][40];  // [m][k], +8 pad -> 2-way max (free)
    __shared__ __align__(16) __bf16 Bs[64][40];  // [n][k]

    const int zi  = blockIdx.z;
    const int tid = threadIdx.x;
    const int m0 = blockIdx.y << 6, n0 = blockIdx.x << 6;

    // staging map: 4 threads per row, each 8 contiguous k (16B bf16 / 32B fp32)
    const int row = tid >> 2;        // 0..63
    const int kc  = (tid & 3) << 3;  // 0,8,16,24

    const __bf16* Bp = p.BT[zi] + (size_t)(n0 + row) * Kdim + kc;
    const float*  Afp = nullptr;
    const __bf16* Abp = nullptr;
    float s = 1.0f;
    if (AFP32) {
        Afp = (const float*)p.A[zi] + (size_t)(m0 + row) * Kdim + kc;
        s = p.scale[zi][m0 + row];
    } else {
        Abp = (const __bf16*)p.A[zi] + (size_t)(m0 + row) * Kdim + kc;
    }

    const int wave = tid >> 6, lane = tid & 63;
    const int moff = (wave >> 1) << 5, noff = (wave & 1) << 5;
    const int lrow = lane & 15, quad = lane >> 4;

    f32x4_t acc00 = {0.f, 0.f, 0.f, 0.f};
    f32x4_t acc01 = {0.f, 0.f, 0.f, 0.f};
    f32x4_t acc10 = {0.f, 0.f, 0.f, 0.f};
    f32x4_t acc11 = {0.f, 0.f, 0.f, 0.f};

    for (int kt = 0; kt < Kdim; kt += 32) {
        bf16_8 a8, b8;
        b8 = *(const bf16_8*)(Bp + kt);
        if (AFP32) {
            float4 f0 = *(const float4*)(Afp + kt);
            float4 f1 = *(const float4*)(Afp + kt + 4);
            a8[0] = (__bf16)(f0.x * s); a8[1] = (__bf16)(f0.y * s);
            a8[2] = (__bf16)(f0.z * s); a8[3] = (__bf16)(f0.w * s);
            a8[4] = (__bf16)(f1.x * s); a8[5] = (__bf16)(f1.y * s);
            a8[6] = (__bf16)(f1.z * s); a8[7] = (__bf16)(f1.w * s);
        } else {
            a8 = *(const bf16_8*)(Abp + kt);
        }
        __syncthreads();   // previous iter's frag reads done before overwrite
        *(bf16_8*)&As[row][kc] = a8;
        *(bf16_8*)&Bs[row][kc] = b8;
        __syncthreads();
        bf16_8 a0 = *(const bf16_8*)&As[moff + lrow][quad << 3];
        bf16_8 a1 = *(const bf16_8*)&As[moff + 16 + lrow][quad << 3];
        bf16_8 b0 = *(const bf16_8*)&Bs[noff + lrow][quad << 3];
        bf16_8 b1 = *(const bf16_8*)&Bs[noff + 16 + lrow][quad << 3];
        acc00 = __builtin_amdgcn_mfma_f32_16x16x32_bf16(a0, b0, acc00, 0, 0, 0);
        acc01 = __builtin_amdgcn_mfma_f32_16x16x32_bf16(a0, b1, acc01, 0, 0, 0);
        acc10 = __builtin_amdgcn_mfma_f32_16x16x32_bf16(a1, b0, acc10, 0, 0, 0);
        acc11 = __builtin_amdgcn_mfma_f32_16x16x32_bf16(a1, b1, acc11, 0, 0, 0);
    }

    const float* bias = p.bias[zi];
    f32x4_t accs[2][2] = {{acc00, acc01}, {acc10, acc11}};
#pragma unroll
    for (int ti = 0; ti < 2; ++ti) {
#pragma unroll
        for (int tj = 0; tj < 2; ++tj) {
            int colg = n0 + noff + (tj << 4) + lrow;
            float bv = bias[colg];
#pragma unroll
            for (int r = 0; r < 4; ++r) {
                int rowg = m0 + moff + (ti << 4) + (quad << 2) + r;
                float v = accs[ti][tj][r] + bv;
                if (GELU) v = 0.5f * v * (1.0f + erff(v * 0.70710678118654752f));
                if (OUTBF16)
                    ((__bf16*)p.C[zi])[(size_t)rowg * ldc + colg] = (__bf16)v;
                else
                    ((float*)p.C[zi])[(size_t)rowg * ldc + colg] = v;
            }
        }
    }
}

extern "C" void kernel_launch(void* const* d_in, const int* in_sizes, int n_in,
                              void* d_out, int out_size, void* d_ws, size_t ws_size,
                              hipStream_t stream) {
    const float* x_v  = (const float*)d_in[0];
    const float* x_a  = (const float*)d_in[1];
    const float* W1v  = (const float*)d_in[2];
    const float* b1v  = (const float*)d_in[3];
    const float* W1a  = (const float*)d_in[4];
    const float* b1a  = (const float*)d_in[5];
    const float* Wmv  = (const float*)d_in[6];
    const float* bmv  = (const float*)d_in[7];
    const float* Wma  = (const float*)d_in[8];
    const float* bma  = (const float*)d_in[9];
    const float* Wout = (const float*)d_in[10];
    const float* bout = (const float*)d_in[11];
    float* out = (float*)d_out;

    char* w = (char*)d_ws;
    auto alloc = [&](size_t bytes) {
        char* r = w;
        w += (bytes + 255) & ~(size_t)255;
        return (void*)r;
    };
    float*  dv    = (float*)alloc(512 * 4);
    float*  da    = (float*)alloc(512 * 4);
    __bf16* WT1v  = (__bf16*)alloc((size_t)Hdim * Ddim * 2);        // [2048][512]
    __bf16* WT1a  = (__bf16*)alloc((size_t)Hdim * Ddim * 2);
    __bf16* WTmv  = (__bf16*)alloc((size_t)Ddim * Hdim * 2);        // [512][2048]
    __bf16* WTma  = (__bf16*)alloc((size_t)Ddim * Hdim * 2);
    __bf16* WTout = (__bf16*)alloc((size_t)Ddim * 2 * Ddim * 2);    // [512][1024]
    __bf16* g1v   = (__bf16*)alloc((size_t)Mrows * Hdim * 2);       // [512][2048]
    __bf16* g1a   = (__bf16*)alloc((size_t)Mrows * Hdim * 2);
    __bf16* comb  = (__bf16*)alloc((size_t)Mrows * 2 * Ddim * 2);   // [512][1024]

    // 1) distance means
    dist_kernel<<<dim3(256), dim3(256), 0, stream>>>(x_v, x_a, dv, da);

    // 2) all weight transpose+casts in one launch
    TPtrs tp;
    tp.src[0] = W1v;  tp.dst[0] = WT1v;
    tp.src[1] = W1a;  tp.dst[1] = WT1a;
    tp.src[2] = Wmv;  tp.dst[2] = WTmv;
    tp.src[3] = Wma;  tp.dst[3] = WTma;
    tp.src[4] = Wout; tp.dst[4] = WTout;
    transpose_all<<<dim3(4608), dim3(256), 0, stream>>>(tp);

    // 3) g1 = gelu(diag(d)*x @ W1 + b1)   [512,2048] bf16, z fuses v/a
    GPtrs g1;
    g1.A[0] = x_v; g1.A[1] = x_a;
    g1.BT[0] = WT1v; g1.BT[1] = WT1a;
    g1.bias[0] = b1v; g1.bias[1] = b1a;
    g1.scale[0] = dv; g1.scale[1] = da;
    g1.C[0] = g1v; g1.C[1] = g1a;
    mfma_gemm<1, 1, 1><<<dim3(Hdim / 64, Mrows / 64, 2), dim3(256), 0, stream>>>(
        g1, Ddim, Hdim);

    // 4) comb[:, :512] = g1v @ Wmv + bmv ; comb[:, 512:] = g1a @ Wma + bma
    GPtrs g2;
    g2.A[0] = g1v; g2.A[1] = g1a;
    g2.BT[0] = WTmv; g2.BT[1] = WTma;
    g2.bias[0] = bmv; g2.bias[1] = bma;
    g2.scale[0] = nullptr; g2.scale[1] = nullptr;
    g2.C[0] = comb; g2.C[1] = comb + Ddim;
    mfma_gemm<0, 0, 1><<<dim3(Ddim / 64, Mrows / 64, 2), dim3(256), 0, stream>>>(
        g2, Hdim, 2 * Ddim);

    // 5) out = comb @ Wout + bout   [512, 512] fp32
    GPtrs g3;
    g3.A[0] = comb; g3.A[1] = comb;
    g3.BT[0] = WTout; g3.BT[1] = WTout;
    g3.bias[0] = bout; g3.bias[1] = bout;
    g3.scale[0] = nullptr; g3.scale[1] = nullptr;
    g3.C[0] = out; g3.C[1] = out;
    mfma_gemm<0, 0, 0><<<dim3(Ddim / 64, Mrows / 64, 1), dim3(256), 0, stream>>>(
        g3, 2 * Ddim, Ddim);
}